// Round 5
// baseline (360.227 us; speedup 1.0000x reference)
//
#include <hip/hip_runtime.h>
#include <hip/hip_bf16.h>

// MLPDecoder: scores[e] = relu((h[src]*h[dst]) @ W1 + b1) @ W2 + b2
// E=300000, D=256. bf16 MFMA, 1-barrier/iter pipeline.
// R1: latency theory (Occ 34.5%) -> grid bump: NEUTRAL.
// R2 FAILED: lb(512,8) clamped VGPR->32, spilled (WRITE 142MB, 241us).
// R3 NEUTRAL: GRID=1024+lb(512,4): 78us. Occupancy is NOT the lever.
// R4 NEUTRAL: no-vmcnt-drain barrier + MFMA-first order: 77us. Schedule is
// NOT the lever either.
// R5: per-pipe arithmetic shows LDS-PIPE-BOUND: 8 waves re-read the same
// 16KB A-tile (128KB/tile) + 6M conflict cyc + 256 bpermutes/tile ~= 45us
// of the 77. MFMA is only ~5us. Fix: wave owns 64 N-cols (Bf[4][8]=128
// VGPR), 4 waves cover N=256 -> BLK=256, GRID=512. LDS reads halve,
// butterfly halves, VALU epilogue halves. Pred: dur 77->~50us, VGPR~220,
// WRITE_SIZE stays 1.2MB (spill = abort signal).

#define E_EDGES 300000
#define DIM 256
#define MT 32                    // edges per block-iteration
#define NTILES (E_EDGES / MT)    // 9375
#define BLK 256                  // 4 waves; each wave owns 64 N-cols
#define GRID_MAIN 512            // 2 blocks/CU
#define MAXJ 19                  // ceil(9375/512)

typedef short bf16x8 __attribute__((ext_vector_type(8)));
typedef float f32x4 __attribute__((ext_vector_type(4)));

__device__ __forceinline__ ushort f2bf(float f) {
    union { float f; unsigned u; } v; v.f = f;
    unsigned r = v.u + 0x7FFFu + ((v.u >> 16) & 1u);  // RNE
    return (ushort)(r >> 16);
}

// Barrier that does NOT drain vmcnt (LDS producers covered by lgkmcnt(0)).
__device__ __forceinline__ void barrier_lgkm() {
    asm volatile("s_waitcnt lgkmcnt(0)" ::: "memory");
    asm volatile("s_barrier" ::: "memory");
}

// W1 fp32 [K=256][N=256] -> W1^T bf16 [N][K]
__global__ void prep_w1t(const float* __restrict__ w1, ushort* __restrict__ w1t) {
    int idx = blockIdx.x * 256 + threadIdx.x;
    int k = idx >> 8, n = idx & 255;
    w1t[n * 256 + k] = f2bf(w1[k * 256 + n]);
}

// h fp32 -> bf16
__global__ void prep_hbf(const float* __restrict__ h, ushort* __restrict__ hbf) {
    int i = blockIdx.x * 256 + threadIdx.x;
    const float4* src = (const float4*)h + (size_t)i * 2;
    float4 a = src[0], b = src[1];
    union { ushort s[8]; uint4 v; } o;
    o.s[0] = f2bf(a.x); o.s[1] = f2bf(a.y); o.s[2] = f2bf(a.z); o.s[3] = f2bf(a.w);
    o.s[4] = f2bf(b.x); o.s[5] = f2bf(b.y); o.s[6] = f2bf(b.z); o.s[7] = f2bf(b.w);
    ((uint4*)hbf)[i] = o.v;
}

__global__ __launch_bounds__(BLK, 4)
void decoder(const ushort* __restrict__ hbf, const int2* __restrict__ edges,
             const ushort* __restrict__ w1t, const float* __restrict__ b1,
             const float* __restrict__ w2, const float* __restrict__ b2p,
             float* __restrict__ out) {
    // stride 264: bank spread for b128 ops; double-buffered
    __shared__ ushort xlds[2][MT][264];   // 33.8 KB
    __shared__ float part[2][4][MT];      // 1 KB
    __shared__ int2 eld[MAXJ * MT];       // this block's edge pairs (4.9 KB)

    const int t = threadIdx.x;
    const int w = t >> 6, lane = t & 63, quad = lane >> 4, l15 = lane & 15;
    const int bx = blockIdx.x, gdim = gridDim.x;
    const int J = (NTILES - bx + gdim - 1) / gdim;   // 18 or 19 tiles

    // ---- register-resident W1 frags: wave w owns N cols [64w, 64w+64) ----
    // B-frag (16x16x32): lane holds B[k = quad*8 + j][n = lane&15]
    bf16x8 Bf[4][8];   // 128 regs, loop indices all compile-time
#pragma unroll
    for (int nt = 0; nt < 4; ++nt) {
        int n = w * 64 + nt * 16 + l15;
#pragma unroll
        for (int ks = 0; ks < 8; ++ks)
            Bf[nt][ks] = *(const bf16x8*)(w1t + n * 256 + ks * 32 + quad * 8);
    }
    float b1v[4], w2v[4];
#pragma unroll
    for (int nt = 0; nt < 4; ++nt) {
        int n = w * 64 + nt * 16 + l15;
        b1v[nt] = b1[n];
        w2v[nt] = w2[n];
    }
    const float b2v = b2p[0];

    // ---- preload ALL this block's edge pairs into LDS ----
    for (int idx = t; idx < J * MT; idx += BLK)
        eld[idx] = edges[(size_t)(bx + (idx >> 5) * gdim) * MT + (idx & 31)];
    __syncthreads();

    const int sm = t >> 3;     // edge row in tile 0..31
    const int sc = t & 7;      // 64B chunk in row

    // single prefetch set; plain named regs (no spill risk).
    uint4 s0, s1, s2, s3, d0, d1, d2, d3;

    auto issue = [&](int j) {
        int2 ed = eld[j * MT + sm];
        const uint4* ps = (const uint4*)(hbf + (size_t)ed.x * DIM) + sc * 4;
        const uint4* pd = (const uint4*)(hbf + (size_t)ed.y * DIM) + sc * 4;
        s0 = ps[0]; s1 = ps[1]; s2 = ps[2]; s3 = ps[3];
        d0 = pd[0]; d1 = pd[1]; d2 = pd[2]; d3 = pd[3];
    };
    auto mul8 = [](uint4 a, uint4 b) -> uint4 {
        union U { uint4 v; __hip_bfloat162 h[4]; } ua, ub, o;
        ua.v = a; ub.v = b;
#pragma unroll
        for (int q = 0; q < 4; ++q) o.h[q] = __hmul2(ua.h[q], ub.h[q]);
        return o.v;
    };
    auto had = [&](int buf) {             // consume prefetch regs -> xlds[buf]
        uint4* dst = (uint4*)&xlds[buf][sm][sc * 32];
        dst[0] = mul8(s0, d0);
        dst[1] = mul8(s1, d1);
        dst[2] = mul8(s2, d2);
        dst[3] = mul8(s3, d3);
    };
    auto finalize = [&](int j, int par) { // write out tile j from part[par]
        if (t < MT) {
            float s = b2v;
#pragma unroll
            for (int ww = 0; ww < 4; ++ww) s += part[par][ww][t];
            out[(size_t)(bx + j * gdim) * MT + t] = s;
        }
    };

    // prologue
    issue(0);
    had(0);                   // xlds[0] <- tile 0 (visible after first barrier)
    if (J > 1) issue(1);

    for (int j = 0; j < J; ++j) {
        const int par = j & 1;
        barrier_lgkm();                   // does NOT drain vmcnt
        if (j > 0) finalize(j - 1, par ^ 1);

        // ---- MFMA on tile j from xlds[par] (overlaps in-flight gathers) ----
        f32x4 acc[2][4];
#pragma unroll
        for (int ms = 0; ms < 2; ++ms)
#pragma unroll
            for (int nt = 0; nt < 4; ++nt)
                acc[ms][nt] = (f32x4){0.f, 0.f, 0.f, 0.f};
        const ushort* xb = &xlds[par][0][0];
#pragma unroll
        for (int ks = 0; ks < 8; ++ks) {
            int kb = ks * 32 + quad * 8;
            bf16x8 a0 = *(const bf16x8*)(xb + l15 * 264 + kb);
            bf16x8 a1 = *(const bf16x8*)(xb + (16 + l15) * 264 + kb);
#pragma unroll
            for (int nt = 0; nt < 4; ++nt) {
                acc[0][nt] = __builtin_amdgcn_mfma_f32_16x16x32_bf16(a0, Bf[nt][ks], acc[0][nt], 0, 0, 0);
                acc[1][nt] = __builtin_amdgcn_mfma_f32_16x16x32_bf16(a1, Bf[nt][ks], acc[1][nt], 0, 0, 0);
            }
        }
        // epilogue: relu(hid+b1).w2, butterfly over 16 n-lanes
        // C/D: row m = ms*16 + quad*4 + r, col n = w*64 + nt*16 + l15
        float red[2][4];
#pragma unroll
        for (int ms = 0; ms < 2; ++ms)
#pragma unroll
            for (int r = 0; r < 4; ++r) {
                float s = 0.f;
#pragma unroll
                for (int nt = 0; nt < 4; ++nt)
                    s += fmaxf(acc[ms][nt][r] + b1v[nt], 0.f) * w2v[nt];
                red[ms][r] = s;
            }
#pragma unroll
        for (int mask = 1; mask <= 8; mask <<= 1)
#pragma unroll
            for (int ms = 0; ms < 2; ++ms)
#pragma unroll
                for (int r = 0; r < 4; ++r)
                    red[ms][r] += __shfl_xor(red[ms][r], mask);
        if (l15 == 0)
#pragma unroll
            for (int ms = 0; ms < 2; ++ms)
#pragma unroll
                for (int r = 0; r < 4; ++r)
                    part[par][w][ms * 16 + quad * 4 + r] = red[ms][r];

        // ---- consume prefetch regs (vmcnt wait lands after MFMA) ----
        if (j + 1 < J) had(par ^ 1);      // xlds[par^1] <- tile j+1
        if (j + 2 < J) issue(j + 2);      // in flight across next barrier
    }

    __syncthreads();
    finalize(J - 1, (J - 1) & 1);
}

// fp32-gather fallback (only if ws too small for hbf; not expected to run)
__global__ __launch_bounds__(512, 4)
void decoder_f32(const float* __restrict__ h, const int2* __restrict__ edges,
                 const ushort* __restrict__ w1t, const float* __restrict__ b1,
                 const float* __restrict__ w2, const float* __restrict__ b2p,
                 float* __restrict__ out) {
    __shared__ ushort xlds[MT][264];
    __shared__ float part[8][MT];
    const int t = threadIdx.x;
    const int w = t >> 6, lane = t & 63, quad = lane >> 4, l15 = lane & 15;
    bf16x8 Bf[2][8];
#pragma unroll
    for (int nt = 0; nt < 2; ++nt)
#pragma unroll
        for (int ks = 0; ks < 8; ++ks)
            Bf[nt][ks] = *(const bf16x8*)(w1t + (w * 32 + nt * 16 + l15) * 256 + ks * 32 + quad * 8);
    float b1v[2], w2v[2];
#pragma unroll
    for (int nt = 0; nt < 2; ++nt) {
        b1v[nt] = b1[w * 32 + nt * 16 + l15];
        w2v[nt] = w2[w * 32 + nt * 16 + l15];
    }
    const float b2v = b2p[0];
    const int sm = t >> 4, sc = t & 15;
    for (int mb = blockIdx.x; mb < NTILES; mb += gridDim.x) {
        int2 ed = edges[mb * MT + sm];
        const float4* ps = (const float4*)(h + (size_t)ed.x * DIM) + sc * 4;
        const float4* pd = (const float4*)(h + (size_t)ed.y * DIM) + sc * 4;
        union { ushort s[16]; uint4 v[2]; } o;
#pragma unroll
        for (int jj = 0; jj < 4; ++jj) {
            float4 a = ps[jj], b = pd[jj];
            o.s[4 * jj + 0] = f2bf(a.x * b.x); o.s[4 * jj + 1] = f2bf(a.y * b.y);
            o.s[4 * jj + 2] = f2bf(a.z * b.z); o.s[4 * jj + 3] = f2bf(a.w * b.w);
        }
        uint4* dst = (uint4*)&xlds[sm][sc * 16];
        dst[0] = o.v[0]; dst[1] = o.v[1];
        __syncthreads();
        f32x4 acc[2][2];
#pragma unroll
        for (int ms = 0; ms < 2; ++ms)
#pragma unroll
            for (int nt = 0; nt < 2; ++nt) acc[ms][nt] = (f32x4){0.f,0.f,0.f,0.f};
#pragma unroll
        for (int ks = 0; ks < 8; ++ks) {
            int kb = ks * 32 + quad * 8;
            bf16x8 a0 = *(const bf16x8*)&xlds[l15][kb];
            bf16x8 a1 = *(const bf16x8*)&xlds[16 + l15][kb];
#pragma unroll
            for (int nt = 0; nt < 2; ++nt) {
                acc[0][nt] = __builtin_amdgcn_mfma_f32_16x16x32_bf16(a0, Bf[nt][ks], acc[0][nt], 0, 0, 0);
                acc[1][nt] = __builtin_amdgcn_mfma_f32_16x16x32_bf16(a1, Bf[nt][ks], acc[1][nt], 0, 0, 0);
            }
        }
        float red[2][4];
#pragma unroll
        for (int ms = 0; ms < 2; ++ms)
#pragma unroll
            for (int r = 0; r < 4; ++r) {
                float s = 0.f;
#pragma unroll
                for (int nt = 0; nt < 2; ++nt)
                    s += fmaxf(acc[ms][nt][r] + b1v[nt], 0.f) * w2v[nt];
                red[ms][r] = s;
            }
#pragma unroll
        for (int mask = 1; mask <= 8; mask <<= 1)
#pragma unroll
            for (int ms = 0; ms < 2; ++ms)
#pragma unroll
                for (int r = 0; r < 4; ++r)
                    red[ms][r] += __shfl_xor(red[ms][r], mask);
        if (l15 == 0)
#pragma unroll
            for (int ms = 0; ms < 2; ++ms)
#pragma unroll
                for (int r = 0; r < 4; ++r)
                    part[w][ms * 16 + quad * 4 + r] = red[ms][r];
        __syncthreads();
        if (t < MT) {
            float s = b2v;
#pragma unroll
            for (int ww = 0; ww < 8; ++ww) s += part[ww][t];
            out[mb * MT + t] = s;
        }
    }
}

extern "C" void kernel_launch(void* const* d_in, const int* in_sizes, int n_in,
                              void* d_out, int out_size, void* d_ws, size_t ws_size,
                              hipStream_t stream) {
    const float* h     = (const float*)d_in[0];
    const int2*  edges = (const int2*)d_in[1];
    const float* W1    = (const float*)d_in[2];
    const float* b1    = (const float*)d_in[3];
    const float* W2    = (const float*)d_in[4];
    const float* b2    = (const float*)d_in[5];
    float* out = (float*)d_out;

    ushort* w1t = (ushort*)d_ws;                     // 128 KB
    ushort* hbf = (ushort*)((char*)d_ws + 131072);   // 51.2 MB

    prep_w1t<<<256, 256, 0, stream>>>(W1, w1t);
    if (ws_size >= 131072 + (size_t)25600000 * 2) {
        prep_hbf<<<12500, 256, 0, stream>>>(h, hbf);
        decoder<<<GRID_MAIN, BLK, 0, stream>>>(hbf, edges, w1t, b1, W2, b2, out);
    } else {
        decoder_f32<<<512, 512, 0, stream>>>(h, edges, w1t, b1, W2, b2, out);
    }
}

// Round 6
// 220.815 us; speedup vs baseline: 1.6313x; 1.6313x over previous
//
#include <hip/hip_runtime.h>
#include <hip/hip_bf16.h>

// MLPDecoder: scores[e] = relu((h[src]*h[dst]) @ W1 + b1) @ W2 + b2
// E=300000, D=256. bf16 MFMA, 1-barrier/iter pipeline.
// R1: latency theory (Occ 34.5%) -> grid bump: NEUTRAL.
// R2 FAILED: lb(512,8) clamped VGPR->32, spilled (WRITE 142MB, 241us).
// R3 NEUTRAL: GRID=1024+lb(512,4): 78us. Occupancy is NOT the lever.
// R4 NEUTRAL: no-vmcnt-drain barrier + MFMA-first order: 77us.
// R5 FAILED: 64-col waves with lb(256,4) -> VGPR cap 512/4=128 < needed
// ~217 -> clamped to 64, spilled (FETCH 663MB, WRITE 59.5MB, 207us). The
// LDS-bound theory was never actually tested.
// R6: same 64-col structure, lb(256,2) -> VGPR cap 256. Bf[4][8]=128 +
// acc 32 + prefetch 32 + misc ~= 217 fits. LDS traffic/tile: 144KB (R4)
// -> 80KB. Pred: VGPR ~220 (64 = abort), WRITE ~1.2MB, conflicts 6M->3M,
// MfmaUtil 20->30-40%, dur 77->~55us.

#define E_EDGES 300000
#define DIM 256
#define MT 32                    // edges per block-iteration
#define NTILES (E_EDGES / MT)    // 9375
#define BLK 256                  // 4 waves; each wave owns 64 N-cols
#define GRID_MAIN 512            // 2 blocks/CU
#define MAXJ 19                  // ceil(9375/512)

typedef short bf16x8 __attribute__((ext_vector_type(8)));
typedef float f32x4 __attribute__((ext_vector_type(4)));

__device__ __forceinline__ ushort f2bf(float f) {
    union { float f; unsigned u; } v; v.f = f;
    unsigned r = v.u + 0x7FFFu + ((v.u >> 16) & 1u);  // RNE
    return (ushort)(r >> 16);
}

// Barrier that does NOT drain vmcnt (LDS producers covered by lgkmcnt(0)).
__device__ __forceinline__ void barrier_lgkm() {
    asm volatile("s_waitcnt lgkmcnt(0)" ::: "memory");
    asm volatile("s_barrier" ::: "memory");
}

// W1 fp32 [K=256][N=256] -> W1^T bf16 [N][K]
__global__ void prep_w1t(const float* __restrict__ w1, ushort* __restrict__ w1t) {
    int idx = blockIdx.x * 256 + threadIdx.x;
    int k = idx >> 8, n = idx & 255;
    w1t[n * 256 + k] = f2bf(w1[k * 256 + n]);
}

// h fp32 -> bf16
__global__ void prep_hbf(const float* __restrict__ h, ushort* __restrict__ hbf) {
    int i = blockIdx.x * 256 + threadIdx.x;
    const float4* src = (const float4*)h + (size_t)i * 2;
    float4 a = src[0], b = src[1];
    union { ushort s[8]; uint4 v; } o;
    o.s[0] = f2bf(a.x); o.s[1] = f2bf(a.y); o.s[2] = f2bf(a.z); o.s[3] = f2bf(a.w);
    o.s[4] = f2bf(b.x); o.s[5] = f2bf(b.y); o.s[6] = f2bf(b.z); o.s[7] = f2bf(b.w);
    ((uint4*)hbf)[i] = o.v;
}

__global__ __launch_bounds__(BLK, 2)
void decoder(const ushort* __restrict__ hbf, const int2* __restrict__ edges,
             const ushort* __restrict__ w1t, const float* __restrict__ b1,
             const float* __restrict__ w2, const float* __restrict__ b2p,
             float* __restrict__ out) {
    // stride 264: bank spread for b128 ops; double-buffered
    __shared__ ushort xlds[2][MT][264];   // 33.8 KB
    __shared__ float part[2][4][MT];      // 1 KB
    __shared__ int2 eld[MAXJ * MT];       // this block's edge pairs (4.9 KB)

    const int t = threadIdx.x;
    const int w = t >> 6, lane = t & 63, quad = lane >> 4, l15 = lane & 15;
    const int bx = blockIdx.x, gdim = gridDim.x;
    const int J = (NTILES - bx + gdim - 1) / gdim;   // 18 or 19 tiles

    // ---- register-resident W1 frags: wave w owns N cols [64w, 64w+64) ----
    // B-frag (16x16x32): lane holds B[k = quad*8 + j][n = lane&15]
    bf16x8 Bf[4][8];   // 128 regs, loop indices all compile-time
#pragma unroll
    for (int nt = 0; nt < 4; ++nt) {
        int n = w * 64 + nt * 16 + l15;
#pragma unroll
        for (int ks = 0; ks < 8; ++ks)
            Bf[nt][ks] = *(const bf16x8*)(w1t + n * 256 + ks * 32 + quad * 8);
    }
    float b1v[4], w2v[4];
#pragma unroll
    for (int nt = 0; nt < 4; ++nt) {
        int n = w * 64 + nt * 16 + l15;
        b1v[nt] = b1[n];
        w2v[nt] = w2[n];
    }
    const float b2v = b2p[0];

    // ---- preload ALL this block's edge pairs into LDS ----
    for (int idx = t; idx < J * MT; idx += BLK)
        eld[idx] = edges[(size_t)(bx + (idx >> 5) * gdim) * MT + (idx & 31)];
    __syncthreads();

    const int sm = t >> 3;     // edge row in tile 0..31
    const int sc = t & 7;      // 64B chunk in row

    // single prefetch set; plain named regs (no spill risk).
    uint4 s0, s1, s2, s3, d0, d1, d2, d3;

    auto issue = [&](int j) {
        int2 ed = eld[j * MT + sm];
        const uint4* ps = (const uint4*)(hbf + (size_t)ed.x * DIM) + sc * 4;
        const uint4* pd = (const uint4*)(hbf + (size_t)ed.y * DIM) + sc * 4;
        s0 = ps[0]; s1 = ps[1]; s2 = ps[2]; s3 = ps[3];
        d0 = pd[0]; d1 = pd[1]; d2 = pd[2]; d3 = pd[3];
    };
    auto mul8 = [](uint4 a, uint4 b) -> uint4 {
        union U { uint4 v; __hip_bfloat162 h[4]; } ua, ub, o;
        ua.v = a; ub.v = b;
#pragma unroll
        for (int q = 0; q < 4; ++q) o.h[q] = __hmul2(ua.h[q], ub.h[q]);
        return o.v;
    };
    auto had = [&](int buf) {             // consume prefetch regs -> xlds[buf]
        uint4* dst = (uint4*)&xlds[buf][sm][sc * 32];
        dst[0] = mul8(s0, d0);
        dst[1] = mul8(s1, d1);
        dst[2] = mul8(s2, d2);
        dst[3] = mul8(s3, d3);
    };
    auto finalize = [&](int j, int par) { // write out tile j from part[par]
        if (t < MT) {
            float s = b2v;
#pragma unroll
            for (int ww = 0; ww < 4; ++ww) s += part[par][ww][t];
            out[(size_t)(bx + j * gdim) * MT + t] = s;
        }
    };

    // prologue
    issue(0);
    had(0);                   // xlds[0] <- tile 0 (visible after first barrier)
    if (J > 1) issue(1);

    for (int j = 0; j < J; ++j) {
        const int par = j & 1;
        barrier_lgkm();                   // does NOT drain vmcnt
        if (j > 0) finalize(j - 1, par ^ 1);

        // ---- MFMA on tile j from xlds[par] (overlaps in-flight gathers) ----
        f32x4 acc[2][4];
#pragma unroll
        for (int ms = 0; ms < 2; ++ms)
#pragma unroll
            for (int nt = 0; nt < 4; ++nt)
                acc[ms][nt] = (f32x4){0.f, 0.f, 0.f, 0.f};
        const ushort* xb = &xlds[par][0][0];
#pragma unroll
        for (int ks = 0; ks < 8; ++ks) {
            int kb = ks * 32 + quad * 8;
            bf16x8 a0 = *(const bf16x8*)(xb + l15 * 264 + kb);
            bf16x8 a1 = *(const bf16x8*)(xb + (16 + l15) * 264 + kb);
#pragma unroll
            for (int nt = 0; nt < 4; ++nt) {
                acc[0][nt] = __builtin_amdgcn_mfma_f32_16x16x32_bf16(a0, Bf[nt][ks], acc[0][nt], 0, 0, 0);
                acc[1][nt] = __builtin_amdgcn_mfma_f32_16x16x32_bf16(a1, Bf[nt][ks], acc[1][nt], 0, 0, 0);
            }
        }
        // epilogue: relu(hid+b1).w2, butterfly over 16 n-lanes
        // C/D: row m = ms*16 + quad*4 + r, col n = w*64 + nt*16 + l15
        float red[2][4];
#pragma unroll
        for (int ms = 0; ms < 2; ++ms)
#pragma unroll
            for (int r = 0; r < 4; ++r) {
                float s = 0.f;
#pragma unroll
                for (int nt = 0; nt < 4; ++nt)
                    s += fmaxf(acc[ms][nt][r] + b1v[nt], 0.f) * w2v[nt];
                red[ms][r] = s;
            }
#pragma unroll
        for (int mask = 1; mask <= 8; mask <<= 1)
#pragma unroll
            for (int ms = 0; ms < 2; ++ms)
#pragma unroll
                for (int r = 0; r < 4; ++r)
                    red[ms][r] += __shfl_xor(red[ms][r], mask);
        if (l15 == 0)
#pragma unroll
            for (int ms = 0; ms < 2; ++ms)
#pragma unroll
                for (int r = 0; r < 4; ++r)
                    part[par][w][ms * 16 + quad * 4 + r] = red[ms][r];

        // ---- consume prefetch regs (vmcnt wait lands after MFMA) ----
        if (j + 1 < J) had(par ^ 1);      // xlds[par^1] <- tile j+1
        if (j + 2 < J) issue(j + 2);      // in flight across next barrier
    }

    __syncthreads();
    finalize(J - 1, (J - 1) & 1);
}

// fp32-gather fallback (only if ws too small for hbf; not expected to run)
__global__ __launch_bounds__(512, 4)
void decoder_f32(const float* __restrict__ h, const int2* __restrict__ edges,
                 const ushort* __restrict__ w1t, const float* __restrict__ b1,
                 const float* __restrict__ w2, const float* __restrict__ b2p,
                 float* __restrict__ out) {
    __shared__ ushort xlds[MT][264];
    __shared__ float part[8][MT];
    const int t = threadIdx.x;
    const int w = t >> 6, lane = t & 63, quad = lane >> 4, l15 = lane & 15;
    bf16x8 Bf[2][8];
#pragma unroll
    for (int nt = 0; nt < 2; ++nt)
#pragma unroll
        for (int ks = 0; ks < 8; ++ks)
            Bf[nt][ks] = *(const bf16x8*)(w1t + (w * 32 + nt * 16 + l15) * 256 + ks * 32 + quad * 8);
    float b1v[2], w2v[2];
#pragma unroll
    for (int nt = 0; nt < 2; ++nt) {
        b1v[nt] = b1[w * 32 + nt * 16 + l15];
        w2v[nt] = w2[w * 32 + nt * 16 + l15];
    }
    const float b2v = b2p[0];
    const int sm = t >> 4, sc = t & 15;
    for (int mb = blockIdx.x; mb < NTILES; mb += gridDim.x) {
        int2 ed = edges[mb * MT + sm];
        const float4* ps = (const float4*)(h + (size_t)ed.x * DIM) + sc * 4;
        const float4* pd = (const float4*)(h + (size_t)ed.y * DIM) + sc * 4;
        union { ushort s[16]; uint4 v[2]; } o;
#pragma unroll
        for (int jj = 0; jj < 4; ++jj) {
            float4 a = ps[jj], b = pd[jj];
            o.s[4 * jj + 0] = f2bf(a.x * b.x); o.s[4 * jj + 1] = f2bf(a.y * b.y);
            o.s[4 * jj + 2] = f2bf(a.z * b.z); o.s[4 * jj + 3] = f2bf(a.w * b.w);
        }
        uint4* dst = (uint4*)&xlds[sm][sc * 16];
        dst[0] = o.v[0]; dst[1] = o.v[1];
        __syncthreads();
        f32x4 acc[2][2];
#pragma unroll
        for (int ms = 0; ms < 2; ++ms)
#pragma unroll
            for (int nt = 0; nt < 2; ++nt) acc[ms][nt] = (f32x4){0.f,0.f,0.f,0.f};
#pragma unroll
        for (int ks = 0; ks < 8; ++ks) {
            int kb = ks * 32 + quad * 8;
            bf16x8 a0 = *(const bf16x8*)&xlds[l15][kb];
            bf16x8 a1 = *(const bf16x8*)&xlds[16 + l15][kb];
#pragma unroll
            for (int nt = 0; nt < 2; ++nt) {
                acc[0][nt] = __builtin_amdgcn_mfma_f32_16x16x32_bf16(a0, Bf[nt][ks], acc[0][nt], 0, 0, 0);
                acc[1][nt] = __builtin_amdgcn_mfma_f32_16x16x32_bf16(a1, Bf[nt][ks], acc[1][nt], 0, 0, 0);
            }
        }
        float red[2][4];
#pragma unroll
        for (int ms = 0; ms < 2; ++ms)
#pragma unroll
            for (int r = 0; r < 4; ++r) {
                float s = 0.f;
#pragma unroll
                for (int nt = 0; nt < 2; ++nt)
                    s += fmaxf(acc[ms][nt][r] + b1v[nt], 0.f) * w2v[nt];
                red[ms][r] = s;
            }
#pragma unroll
        for (int mask = 1; mask <= 8; mask <<= 1)
#pragma unroll
            for (int ms = 0; ms < 2; ++ms)
#pragma unroll
                for (int r = 0; r < 4; ++r)
                    red[ms][r] += __shfl_xor(red[ms][r], mask);
        if (l15 == 0)
#pragma unroll
            for (int ms = 0; ms < 2; ++ms)
#pragma unroll
                for (int r = 0; r < 4; ++r)
                    part[w][ms * 16 + quad * 4 + r] = red[ms][r];
        __syncthreads();
        if (t < MT) {
            float s = b2v;
#pragma unroll
            for (int ww = 0; ww < 8; ++ww) s += part[ww][t];
            out[mb * MT + t] = s;
        }
    }
}

extern "C" void kernel_launch(void* const* d_in, const int* in_sizes, int n_in,
                              void* d_out, int out_size, void* d_ws, size_t ws_size,
                              hipStream_t stream) {
    const float* h     = (const float*)d_in[0];
    const int2*  edges = (const int2*)d_in[1];
    const float* W1    = (const float*)d_in[2];
    const float* b1    = (const float*)d_in[3];
    const float* W2    = (const float*)d_in[4];
    const float* b2    = (const float*)d_in[5];
    float* out = (float*)d_out;

    ushort* w1t = (ushort*)d_ws;                     // 128 KB
    ushort* hbf = (ushort*)((char*)d_ws + 131072);   // 51.2 MB

    prep_w1t<<<256, 256, 0, stream>>>(W1, w1t);
    if (ws_size >= 131072 + (size_t)25600000 * 2) {
        prep_hbf<<<12500, 256, 0, stream>>>(h, hbf);
        decoder<<<GRID_MAIN, BLK, 0, stream>>>(hbf, edges, w1t, b1, W2, b2, out);
    } else {
        decoder_f32<<<512, 512, 0, stream>>>(h, edges, w1t, b1, W2, b2, out);
    }
}